// Round 4
// baseline (220.834 us; speedup 1.0000x reference)
//
#include <hip/hip_runtime.h>
#include <hip/hip_bf16.h>
#include <stdint.h>

#define Bn  2
#define Tn  2048
#define Dn  1024
#define Hn  16
#define DHn 64
#define Mn  (Bn*Tn)

typedef __attribute__((ext_vector_type(8))) short short8;
typedef __attribute__((ext_vector_type(4))) short short4v;
typedef __attribute__((ext_vector_type(4))) float f32x4;

__device__ __forceinline__ f32x4 fzero4() { f32x4 z = {0.f, 0.f, 0.f, 0.f}; return z; }

#define TR16(dst, a32) asm volatile("ds_read_b64_tr_b16 %0, %1" : "=v"(dst) : "v"(a32))

// ---------------- f32 -> bf16, batched ----------------
__global__ void cvt3_kernel(const float* __restrict__ a0, const float* __restrict__ a1,
                            const float* __restrict__ a2,
                            __hip_bfloat16* __restrict__ o0, __hip_bfloat16* __restrict__ o1,
                            __hip_bfloat16* __restrict__ o2, int n)
{
    const int i = (blockIdx.x * blockDim.x + threadIdx.x) * 8;
    if (i >= n) return;
    const float* in = blockIdx.y == 0 ? a0 : (blockIdx.y == 1 ? a1 : a2);
    __hip_bfloat16* out = blockIdx.y == 0 ? o0 : (blockIdx.y == 1 ? o1 : o2);
    float4 a = *(const float4*)(in + i);
    float4 b = *(const float4*)(in + i + 4);
    union { __hip_bfloat16 h[8]; short8 u; } tmp;
    tmp.h[0] = __float2bfloat16(a.x); tmp.h[1] = __float2bfloat16(a.y);
    tmp.h[2] = __float2bfloat16(a.z); tmp.h[3] = __float2bfloat16(a.w);
    tmp.h[4] = __float2bfloat16(b.x); tmp.h[5] = __float2bfloat16(b.y);
    tmp.h[6] = __float2bfloat16(b.z); tmp.h[7] = __float2bfloat16(b.w);
    *(short8*)(out + i) = tmp.u;
}

__global__ void cvt4_kernel(const float* __restrict__ a0, const float* __restrict__ a1,
                            const float* __restrict__ a2, const float* __restrict__ a3,
                            __hip_bfloat16* __restrict__ o0, __hip_bfloat16* __restrict__ o1,
                            __hip_bfloat16* __restrict__ o2, __hip_bfloat16* __restrict__ o3, int n)
{
    const int i = (blockIdx.x * blockDim.x + threadIdx.x) * 8;
    if (i >= n) return;
    const float* in = blockIdx.y == 0 ? a0 : (blockIdx.y == 1 ? a1 : (blockIdx.y == 2 ? a2 : a3));
    __hip_bfloat16* out = blockIdx.y == 0 ? o0 : (blockIdx.y == 1 ? o1 : (blockIdx.y == 2 ? o2 : o3));
    float4 a = *(const float4*)(in + i);
    float4 b = *(const float4*)(in + i + 4);
    union { __hip_bfloat16 h[8]; short8 u; } tmp;
    tmp.h[0] = __float2bfloat16(a.x); tmp.h[1] = __float2bfloat16(a.y);
    tmp.h[2] = __float2bfloat16(a.z); tmp.h[3] = __float2bfloat16(a.w);
    tmp.h[4] = __float2bfloat16(b.x); tmp.h[5] = __float2bfloat16(b.y);
    tmp.h[6] = __float2bfloat16(b.z); tmp.h[7] = __float2bfloat16(b.w);
    *(short8*)(out + i) = tmp.u;
}

// ---------------- fused QKV projection GEMM ----------------
// grid (Mn/128, 24): blockIdx.y selects {q,k,v} group (y>>3) and col block (y&7).
// 128x128 tile, BK=32, global_load_lds(16B), double-buffered LDS.
__global__ __launch_bounds__(256, 2)
void gemm_qkv_kernel(const __hip_bfloat16* __restrict__ qa, const __hip_bfloat16* __restrict__ ka,
                     const __hip_bfloat16* __restrict__ va,
                     const __hip_bfloat16* __restrict__ wq, const __hip_bfloat16* __restrict__ wk,
                     const __hip_bfloat16* __restrict__ wv,
                     const float* __restrict__ bq_, const float* __restrict__ bk_,
                     const float* __restrict__ bv_,
                     __hip_bfloat16* __restrict__ Qp, __hip_bfloat16* __restrict__ Kp,
                     __hip_bfloat16* __restrict__ Vp)
{
    __shared__ alignas(16) short As[2][128*32];
    __shared__ alignas(16) short Bs[2][128*32];
    const int grp = blockIdx.y >> 3;
    const __hip_bfloat16* A  = grp == 0 ? qa : (grp == 1 ? ka : va);
    const __hip_bfloat16* Bw = grp == 0 ? wq : (grp == 1 ? wk : wv);
    const float* bias        = grp == 0 ? bq_ : (grp == 1 ? bk_ : bv_);
    __hip_bfloat16* C        = grp == 0 ? Qp : (grp == 1 ? Kp : Vp);

    const int t = threadIdx.x, lane = t & 63, wave = t >> 6;
    const int wm = wave >> 1, wn = wave & 1;
    const int row0 = blockIdx.x * 128, col0 = (blockIdx.y & 7) * 128;

    f32x4 acc[4][4];
#pragma unroll
    for (int m = 0; m < 4; ++m)
#pragma unroll
        for (int n = 0; n < 4; ++n) acc[m][n] = fzero4();

    const int srow = wave*16 + (lane >> 2);
    const int skk  = (lane & 3) * 8;
    const int ldsb = wave * 1024;

    auto STAGE = [&](int buf, int k0) {
#pragma unroll
        for (int i = 0; i < 2; ++i) {
            __builtin_amdgcn_global_load_lds(
                (const __attribute__((address_space(1))) void*)(A + (size_t)(row0 + i*64 + srow)*Dn + k0 + skk),
                (__attribute__((address_space(3))) void*)((char*)As[buf] + i*4096 + ldsb), 16, 0, 0);
            __builtin_amdgcn_global_load_lds(
                (const __attribute__((address_space(1))) void*)(Bw + (size_t)(col0 + i*64 + srow)*Dn + k0 + skk),
                (__attribute__((address_space(3))) void*)((char*)Bs[buf] + i*4096 + ldsb), 16, 0, 0);
        }
    };

    STAGE(0, 0);
    __syncthreads();
    int cur = 0;
    for (int k0 = 0; k0 < Dn; k0 += 32) {
        if (k0 + 32 < Dn) STAGE(cur ^ 1, k0 + 32);
        short8 af[4], bf_[4];
#pragma unroll
        for (int m = 0; m < 4; ++m)
            af[m] = *(const short8*)((char*)As[cur] + (wm*64 + m*16 + (lane & 15))*64 + (lane >> 4)*16);
#pragma unroll
        for (int n = 0; n < 4; ++n)
            bf_[n] = *(const short8*)((char*)Bs[cur] + (wn*64 + n*16 + (lane & 15))*64 + (lane >> 4)*16);
        __builtin_amdgcn_s_setprio(1);
#pragma unroll
        for (int m = 0; m < 4; ++m)
#pragma unroll
            for (int n = 0; n < 4; ++n)
                acc[m][n] = __builtin_amdgcn_mfma_f32_16x16x32_bf16(af[m], bf_[n], acc[m][n], 0, 0, 0);
        __builtin_amdgcn_s_setprio(0);
        __syncthreads();
        cur ^= 1;
    }

#pragma unroll
    for (int n = 0; n < 4; ++n) {
        const int col = col0 + wn*64 + n*16 + (lane & 15);
        const float bv = bias[col];
#pragma unroll
        for (int m = 0; m < 4; ++m) {
            const int rb_ = row0 + wm*64 + m*16 + (lane>>4)*4;
#pragma unroll
            for (int i = 0; i < 4; ++i)
                C[(size_t)(rb_+i)*Dn + col] = __float2bfloat16(acc[m][n][i] + bv);
        }
    }
}

// ---------------- final GEMM: 64x128 tile, f32 out ----------------
__global__ __launch_bounds__(256, 2)
void gemm_out_kernel(const __hip_bfloat16* __restrict__ A,
                     const __hip_bfloat16* __restrict__ Bw,
                     const float* __restrict__ bias,
                     float* __restrict__ C)
{
    __shared__ alignas(16) short As[2][64*32];
    __shared__ alignas(16) short Bs[2][128*32];
    const int t = threadIdx.x, lane = t & 63, wave = t >> 6;
    const int wm = wave >> 1, wn = wave & 1;
    const int row0 = blockIdx.x * 64, col0 = blockIdx.y * 128;

    f32x4 acc[2][4];
#pragma unroll
    for (int m = 0; m < 2; ++m)
#pragma unroll
        for (int n = 0; n < 4; ++n) acc[m][n] = fzero4();

    const int srow = wave*16 + (lane >> 2);
    const int skk  = (lane & 3) * 8;
    const int ldsb = wave * 1024;

    auto STAGE = [&](int buf, int k0) {
        __builtin_amdgcn_global_load_lds(
            (const __attribute__((address_space(1))) void*)(A + (size_t)(row0 + srow)*Dn + k0 + skk),
            (__attribute__((address_space(3))) void*)((char*)As[buf] + ldsb), 16, 0, 0);
#pragma unroll
        for (int i = 0; i < 2; ++i)
            __builtin_amdgcn_global_load_lds(
                (const __attribute__((address_space(1))) void*)(Bw + (size_t)(col0 + i*64 + srow)*Dn + k0 + skk),
                (__attribute__((address_space(3))) void*)((char*)Bs[buf] + i*4096 + ldsb), 16, 0, 0);
    };

    STAGE(0, 0);
    __syncthreads();
    int cur = 0;
    for (int k0 = 0; k0 < Dn; k0 += 32) {
        if (k0 + 32 < Dn) STAGE(cur ^ 1, k0 + 32);
        short8 af[2], bf_[4];
#pragma unroll
        for (int m = 0; m < 2; ++m)
            af[m] = *(const short8*)((char*)As[cur] + (wm*32 + m*16 + (lane & 15))*64 + (lane >> 4)*16);
#pragma unroll
        for (int n = 0; n < 4; ++n)
            bf_[n] = *(const short8*)((char*)Bs[cur] + (wn*64 + n*16 + (lane & 15))*64 + (lane >> 4)*16);
        __builtin_amdgcn_s_setprio(1);
#pragma unroll
        for (int m = 0; m < 2; ++m)
#pragma unroll
            for (int n = 0; n < 4; ++n)
                acc[m][n] = __builtin_amdgcn_mfma_f32_16x16x32_bf16(af[m], bf_[n], acc[m][n], 0, 0, 0);
        __builtin_amdgcn_s_setprio(0);
        __syncthreads();
        cur ^= 1;
    }

#pragma unroll
    for (int n = 0; n < 4; ++n) {
        const int col = col0 + wn*64 + n*16 + (lane & 15);
        const float bv = bias[col];
#pragma unroll
        for (int m = 0; m < 2; ++m) {
            const int rb_ = row0 + wm*32 + m*16 + (lane>>4)*4;
#pragma unroll
            for (int i = 0; i < 4; ++i)
                C[(size_t)(rb_+i)*Dn + col] = acc[m][n][i] + bv;
        }
    }
}

// ---------------- flash attention fwd ----------------
// grid = B*H*(T/64) = 1024 blocks (4/CU); 4 waves x 16 q-rows; KV tile 64.
// S^T = mfma(K, Q); softmax in-register; l via ones-row MFMA; PV via tr-reads.
#define VPL 1288

__device__ __forceinline__ void attn_tile(
    const short8 (&ck)[4][2], const short8 (&cv)[2],
    short8 (&nk)[4][2], short8 (&nv)[2], int kvn,
    const short8 (&bq)[2], f32x4 (&o_)[4], float& m_, float& l_,
    const __hip_bfloat16* K, const __hip_bfloat16* V, size_t base,
    int c, int g, int vrow, int vc, int vh, int vdst0, uint32_t atr, short* Vlds,
    const short8& ones)
{
    const float cexp = 0.18033688011112042f;   // log2(e)/sqrt(64)

    // prefetch next tile's K and V into registers
    {
        const __hip_bfloat16* kp = K + base + (size_t)(kvn + c) * Dn + g*8;
#pragma unroll
        for (int sub = 0; sub < 4; ++sub)
#pragma unroll
            for (int ks = 0; ks < 2; ++ks)
                nk[sub][ks] = *(const short8*)(kp + (size_t)sub*16*Dn + ks*32);
        const __hip_bfloat16* vp = V + base + (size_t)(kvn + vrow) * Dn + vc*16 + vh*8;
        nv[0] = *(const short8*)vp;
        nv[1] = *(const short8*)(vp + (size_t)32*Dn);
    }

    // S^T = K * Q
    f32x4 s_[4];
#pragma unroll
    for (int sub = 0; sub < 4; ++sub) s_[sub] = fzero4();
    __builtin_amdgcn_s_setprio(1);
#pragma unroll
    for (int sub = 0; sub < 4; ++sub)
#pragma unroll
        for (int ks = 0; ks < 2; ++ks)
            s_[sub] = __builtin_amdgcn_mfma_f32_16x16x32_bf16(ck[sub][ks], bq[ks], s_[sub], 0, 0, 0);
    __builtin_amdgcn_s_setprio(0);

    // online softmax with defer-max; P packed as PV B-fragments
    float rm = s_[0][0];
#pragma unroll
    for (int sub = 0; sub < 4; ++sub)
#pragma unroll
        for (int i = 0; i < 4; ++i) rm = fmaxf(rm, s_[sub][i]);
    rm = fmaxf(rm, __shfl_xor(rm, 16));
    rm = fmaxf(rm, __shfl_xor(rm, 32));
    if (!__all((rm - m_) * cexp <= 8.0f)) {
        const float mn = fmaxf(m_, rm);
        const float sc = exp2f((m_ - mn) * cexp);
        m_ = mn;
        l_ *= sc;
#pragma unroll
        for (int d = 0; d < 4; ++d)
#pragma unroll
            for (int i = 0; i < 4; ++i) o_[d][i] *= sc;
    }
    short8 pa[2];
    const float mn = m_;
#pragma unroll
    for (int kc = 0; kc < 2; ++kc)
#pragma unroll
        for (int hf = 0; hf < 2; ++hf)
#pragma unroll
            for (int i = 0; i < 4; ++i) {
                const float p = exp2f((s_[kc*2+hf][i] - mn) * cexp);
                union { __hip_bfloat16 hb; short u; } cvp;
                cvp.hb = __float2bfloat16(p);
                pa[kc][hf*4 + i] = cvp.u;
            }
    // l-sum via ones-row MFMA (cross-lane sum on the matrix pipe)
    f32x4 accL = __builtin_amdgcn_mfma_f32_16x16x32_bf16(ones, pa[0], fzero4(), 0, 0, 0);
    accL = __builtin_amdgcn_mfma_f32_16x16x32_bf16(ones, pa[1], accL, 0, 0, 0);
    l_ += accL[0];

    // stage current V into LDS (raw barriers: no vmcnt drain)
    __builtin_amdgcn_s_barrier();
    *(short8*)(&Vlds[vdst0])       = cv[0];
    *(short8*)(&Vlds[vdst0 + 640]) = cv[1];
    asm volatile("s_waitcnt lgkmcnt(0)" ::: "memory");
    __builtin_amdgcn_s_barrier();
    __builtin_amdgcn_sched_barrier(0);

    // PV: O^T += V^T * P^T
    short4v tv[4][2][2];
#pragma unroll
    for (int d = 0; d < 4; ++d)
#pragma unroll
        for (int kc = 0; kc < 2; ++kc) {
            const uint32_t a = atr + (uint32_t)(d*2576 + kc*1280);
            TR16(tv[d][kc][0], a);
            TR16(tv[d][kc][1], a + 640);
        }
    asm volatile("s_waitcnt lgkmcnt(0)" ::: "memory");
    __builtin_amdgcn_sched_barrier(0);
    __builtin_amdgcn_s_setprio(1);
#pragma unroll
    for (int d = 0; d < 4; ++d) {
        const short8 av0 = __builtin_shufflevector(tv[d][0][0], tv[d][0][1], 0,1,2,3,4,5,6,7);
        const short8 av1 = __builtin_shufflevector(tv[d][1][0], tv[d][1][1], 0,1,2,3,4,5,6,7);
        o_[d] = __builtin_amdgcn_mfma_f32_16x16x32_bf16(av0, pa[0], o_[d], 0, 0, 0);
        o_[d] = __builtin_amdgcn_mfma_f32_16x16x32_bf16(av1, pa[1], o_[d], 0, 0, 0);
    }
    __builtin_amdgcn_s_setprio(0);
}

__global__ __launch_bounds__(256, 4)
void attn_kernel(const __hip_bfloat16* __restrict__ Q,
                 const __hip_bfloat16* __restrict__ K,
                 const __hip_bfloat16* __restrict__ V,
                 __hip_bfloat16* __restrict__ O)
{
    __shared__ alignas(16) short Vlds[4*VPL];
    const int t = threadIdx.x, lane = t & 63, wave = t >> 6;
    const int g = lane >> 4, c = lane & 15;
    const int blk = blockIdx.x;
    const int qb = blk & 31;
    const int h  = (blk >> 5) & (Hn - 1);
    const int b  = blk >> 9;
    const size_t base = (size_t)b * Tn * Dn + (size_t)h * DHn;
    const int q0 = qb * 64 + wave * 16;

    short8 bq[2];
    {
        const __hip_bfloat16* qp = Q + base + (size_t)(q0 + c) * Dn + g*8;
        bq[0] = *(const short8*)qp;
        bq[1] = *(const short8*)(qp + 32);
    }
    short8 ones;
#pragma unroll
    for (int i = 0; i < 8; ++i) ones[i] = (short)0x3F80;   // bf16 1.0

    f32x4 o_[4];
#pragma unroll
    for (int d = 0; d < 4; ++d) o_[d] = fzero4();
    float m_ = -3e38f, l_ = 0.f;

    const int vrow = t >> 3;
    const int vc   = (t >> 1) & 3;
    const int vh   = t & 1;
    const int vdst0 = vc*VPL + (vrow>>2)*80 + (vrow&3)*16 + vh*8;
    const uint32_t vbase = (uint32_t)(uintptr_t)(void*)Vlds;
    const uint32_t atr = vbase + (uint32_t)(g*160 + c*8);

    short8 akA[4][2], akB[4][2], vrA[2], vrB[2];
    {
        const __hip_bfloat16* kp = K + base + (size_t)c * Dn + g*8;
#pragma unroll
        for (int sub = 0; sub < 4; ++sub)
#pragma unroll
            for (int ks = 0; ks < 2; ++ks)
                akA[sub][ks] = *(const short8*)(kp + (size_t)sub*16*Dn + ks*32);
        const __hip_bfloat16* vp = V + base + (size_t)vrow * Dn + vc*16 + vh*8;
        vrA[0] = *(const short8*)vp;
        vrA[1] = *(const short8*)(vp + (size_t)32*Dn);
    }

    for (int kv0 = 0; kv0 < Tn; kv0 += 128) {
        attn_tile(akA, vrA, akB, vrB, kv0 + 64, bq, o_, m_, l_,
                  K, V, base, c, g, vrow, vc, vh, vdst0, atr, Vlds, ones);
        const int kvn = (kv0 + 128 < Tn) ? kv0 + 128 : 0;
        attn_tile(akB, vrB, akA, vrA, kvn, bq, o_, m_, l_,
                  K, V, base, c, g, vrow, vc, vh, vdst0, atr, Vlds, ones);
    }

    const float inv = 1.f / l_;
    __hip_bfloat16* op = O + base + (size_t)(q0 + c) * Dn + g*4;
#pragma unroll
    for (int d = 0; d < 4; ++d) {
        union { __hip_bfloat16 hb[4]; ushort4 u4; } w;
#pragma unroll
        for (int i = 0; i < 4; ++i) w.hb[i] = __float2bfloat16(o_[d][i] * inv);
        *(ushort4*)(op + d*16) = w.u4;
    }
}

extern "C" void kernel_launch(void* const* d_in, const int* in_sizes, int n_in,
                              void* d_out, int out_size, void* d_ws, size_t ws_size,
                              hipStream_t stream)
{
    (void)in_sizes; (void)n_in; (void)out_size; (void)ws_size;
    const float* q    = (const float*)d_in[0];
    const float* k    = (const float*)d_in[1];
    const float* v    = (const float*)d_in[2];
    const float* wq_w = (const float*)d_in[3];
    const float* wq_b = (const float*)d_in[4];
    const float* wk_w = (const float*)d_in[5];
    const float* wk_b = (const float*)d_in[6];
    const float* wv_w = (const float*)d_in[7];
    const float* wv_b = (const float*)d_in[8];
    const float* wo_w = (const float*)d_in[9];
    const float* wo_b = (const float*)d_in[10];

    char* ws = (char*)d_ws;
    const size_t S1 = (size_t)Mn * Dn * 2;
    const size_t W  = (size_t)Dn * Dn * 2;
    __hip_bfloat16* qb  = (__hip_bfloat16*)(ws);
    __hip_bfloat16* kb  = (__hip_bfloat16*)(ws + S1);
    __hip_bfloat16* vb  = (__hip_bfloat16*)(ws + 2*S1);
    __hip_bfloat16* wqb = (__hip_bfloat16*)(ws + 3*S1);
    __hip_bfloat16* wkb = (__hip_bfloat16*)(ws + 3*S1 + W);
    __hip_bfloat16* wvb = (__hip_bfloat16*)(ws + 3*S1 + 2*W);
    __hip_bfloat16* wob = (__hip_bfloat16*)(ws + 3*S1 + 3*W);
    __hip_bfloat16* Qp  = (__hip_bfloat16*)(ws + 3*S1 + 4*W);
    __hip_bfloat16* Kp  = (__hip_bfloat16*)(ws + 4*S1 + 4*W);
    __hip_bfloat16* Vp  = (__hip_bfloat16*)(ws + 5*S1 + 4*W);
    __hip_bfloat16* Ap  = (__hip_bfloat16*)(ws + 6*S1 + 4*W);

    const int nQKV = Mn * Dn;
    const int nW   = Dn * Dn;
    cvt3_kernel<<<dim3(nQKV/2048, 3), 256, 0, stream>>>(q, k, v, qb, kb, vb, nQKV);
    cvt4_kernel<<<dim3(nW/2048, 4), 256, 0, stream>>>(wq_w, wk_w, wv_w, wo_w,
                                                      wqb, wkb, wvb, wob, nW);

    gemm_qkv_kernel<<<dim3(Mn/128, 24), 256, 0, stream>>>(
        qb, kb, vb, wqb, wkb, wvb, wq_b, wk_b, wv_b, Qp, Kp, Vp);

    attn_kernel<<<Bn*Hn*(Tn/64), 256, 0, stream>>>(Qp, Kp, Vp, Ap);

    gemm_out_kernel<<<dim3(Mn/64, Dn/128), 256, 0, stream>>>(Ap, wob, wo_b, (float*)d_out);
}

// Round 5
// 150.878 us; speedup vs baseline: 1.4637x; 1.4637x over previous
//
#include <hip/hip_runtime.h>
#include <hip/hip_bf16.h>
#include <stdint.h>

#define Bn  2
#define Tn  2048
#define Dn  1024
#define Hn  16
#define DHn 64
#define Mn  (Bn*Tn)

typedef __attribute__((ext_vector_type(8))) short short8;
typedef __attribute__((ext_vector_type(4))) short short4v;
typedef __attribute__((ext_vector_type(4))) float f32x4;

__device__ __forceinline__ f32x4 fzero4() { f32x4 z = {0.f, 0.f, 0.f, 0.f}; return z; }

#define TR16(dst, a32) asm volatile("ds_read_b64_tr_b16 %0, %1" : "=v"(dst) : "v"(a32))

// ---------------- f32 -> bf16, batched ----------------
__global__ void cvt3_kernel(const float* __restrict__ a0, const float* __restrict__ a1,
                            const float* __restrict__ a2,
                            __hip_bfloat16* __restrict__ o0, __hip_bfloat16* __restrict__ o1,
                            __hip_bfloat16* __restrict__ o2, int n)
{
    const int i = (blockIdx.x * blockDim.x + threadIdx.x) * 8;
    if (i >= n) return;
    const float* in = blockIdx.y == 0 ? a0 : (blockIdx.y == 1 ? a1 : a2);
    __hip_bfloat16* out = blockIdx.y == 0 ? o0 : (blockIdx.y == 1 ? o1 : o2);
    float4 a = *(const float4*)(in + i);
    float4 b = *(const float4*)(in + i + 4);
    union { __hip_bfloat16 h[8]; short8 u; } tmp;
    tmp.h[0] = __float2bfloat16(a.x); tmp.h[1] = __float2bfloat16(a.y);
    tmp.h[2] = __float2bfloat16(a.z); tmp.h[3] = __float2bfloat16(a.w);
    tmp.h[4] = __float2bfloat16(b.x); tmp.h[5] = __float2bfloat16(b.y);
    tmp.h[6] = __float2bfloat16(b.z); tmp.h[7] = __float2bfloat16(b.w);
    *(short8*)(out + i) = tmp.u;
}

__global__ void cvt4_kernel(const float* __restrict__ a0, const float* __restrict__ a1,
                            const float* __restrict__ a2, const float* __restrict__ a3,
                            __hip_bfloat16* __restrict__ o0, __hip_bfloat16* __restrict__ o1,
                            __hip_bfloat16* __restrict__ o2, __hip_bfloat16* __restrict__ o3, int n)
{
    const int i = (blockIdx.x * blockDim.x + threadIdx.x) * 8;
    if (i >= n) return;
    const float* in = blockIdx.y == 0 ? a0 : (blockIdx.y == 1 ? a1 : (blockIdx.y == 2 ? a2 : a3));
    __hip_bfloat16* out = blockIdx.y == 0 ? o0 : (blockIdx.y == 1 ? o1 : (blockIdx.y == 2 ? o2 : o3));
    float4 a = *(const float4*)(in + i);
    float4 b = *(const float4*)(in + i + 4);
    union { __hip_bfloat16 h[8]; short8 u; } tmp;
    tmp.h[0] = __float2bfloat16(a.x); tmp.h[1] = __float2bfloat16(a.y);
    tmp.h[2] = __float2bfloat16(a.z); tmp.h[3] = __float2bfloat16(a.w);
    tmp.h[4] = __float2bfloat16(b.x); tmp.h[5] = __float2bfloat16(b.y);
    tmp.h[6] = __float2bfloat16(b.z); tmp.h[7] = __float2bfloat16(b.w);
    *(short8*)(out + i) = tmp.u;
}

// ---------------- fused QKV projection GEMM ----------------
__global__ __launch_bounds__(256, 2)
void gemm_qkv_kernel(const __hip_bfloat16* __restrict__ qa, const __hip_bfloat16* __restrict__ ka,
                     const __hip_bfloat16* __restrict__ va,
                     const __hip_bfloat16* __restrict__ wq, const __hip_bfloat16* __restrict__ wk,
                     const __hip_bfloat16* __restrict__ wv,
                     const float* __restrict__ bq_, const float* __restrict__ bk_,
                     const float* __restrict__ bv_,
                     __hip_bfloat16* __restrict__ Qp, __hip_bfloat16* __restrict__ Kp,
                     __hip_bfloat16* __restrict__ Vp)
{
    __shared__ alignas(16) short As[2][128*32];
    __shared__ alignas(16) short Bs[2][128*32];
    const int grp = blockIdx.y >> 3;
    const __hip_bfloat16* A  = grp == 0 ? qa : (grp == 1 ? ka : va);
    const __hip_bfloat16* Bw = grp == 0 ? wq : (grp == 1 ? wk : wv);
    const float* bias        = grp == 0 ? bq_ : (grp == 1 ? bk_ : bv_);
    __hip_bfloat16* C        = grp == 0 ? Qp : (grp == 1 ? Kp : Vp);

    const int t = threadIdx.x, lane = t & 63, wave = t >> 6;
    const int wm = wave >> 1, wn = wave & 1;
    const int row0 = blockIdx.x * 128, col0 = (blockIdx.y & 7) * 128;

    f32x4 acc[4][4];
#pragma unroll
    for (int m = 0; m < 4; ++m)
#pragma unroll
        for (int n = 0; n < 4; ++n) acc[m][n] = fzero4();

    const int srow = wave*16 + (lane >> 2);
    const int skk  = (lane & 3) * 8;
    const int ldsb = wave * 1024;

    auto STAGE = [&](int buf, int k0) {
#pragma unroll
        for (int i = 0; i < 2; ++i) {
            __builtin_amdgcn_global_load_lds(
                (const __attribute__((address_space(1))) void*)(A + (size_t)(row0 + i*64 + srow)*Dn + k0 + skk),
                (__attribute__((address_space(3))) void*)((char*)As[buf] + i*4096 + ldsb), 16, 0, 0);
            __builtin_amdgcn_global_load_lds(
                (const __attribute__((address_space(1))) void*)(Bw + (size_t)(col0 + i*64 + srow)*Dn + k0 + skk),
                (__attribute__((address_space(3))) void*)((char*)Bs[buf] + i*4096 + ldsb), 16, 0, 0);
        }
    };

    STAGE(0, 0);
    __syncthreads();
    int cur = 0;
    for (int k0 = 0; k0 < Dn; k0 += 32) {
        if (k0 + 32 < Dn) STAGE(cur ^ 1, k0 + 32);
        short8 af[4], bf_[4];
#pragma unroll
        for (int m = 0; m < 4; ++m)
            af[m] = *(const short8*)((char*)As[cur] + (wm*64 + m*16 + (lane & 15))*64 + (lane >> 4)*16);
#pragma unroll
        for (int n = 0; n < 4; ++n)
            bf_[n] = *(const short8*)((char*)Bs[cur] + (wn*64 + n*16 + (lane & 15))*64 + (lane >> 4)*16);
        __builtin_amdgcn_s_setprio(1);
#pragma unroll
        for (int m = 0; m < 4; ++m)
#pragma unroll
            for (int n = 0; n < 4; ++n)
                acc[m][n] = __builtin_amdgcn_mfma_f32_16x16x32_bf16(af[m], bf_[n], acc[m][n], 0, 0, 0);
        __builtin_amdgcn_s_setprio(0);
        __syncthreads();
        cur ^= 1;
    }

#pragma unroll
    for (int n = 0; n < 4; ++n) {
        const int col = col0 + wn*64 + n*16 + (lane & 15);
        const float bv = bias[col];
#pragma unroll
        for (int m = 0; m < 4; ++m) {
            const int rb_ = row0 + wm*64 + m*16 + (lane>>4)*4;
#pragma unroll
            for (int i = 0; i < 4; ++i)
                C[(size_t)(rb_+i)*Dn + col] = __float2bfloat16(acc[m][n][i] + bv);
        }
    }
}

// ---------------- final GEMM: 64x128 tile, f32 out ----------------
__global__ __launch_bounds__(256, 2)
void gemm_out_kernel(const __hip_bfloat16* __restrict__ A,
                     const __hip_bfloat16* __restrict__ Bw,
                     const float* __restrict__ bias,
                     float* __restrict__ C)
{
    __shared__ alignas(16) short As[2][64*32];
    __shared__ alignas(16) short Bs[2][128*32];
    const int t = threadIdx.x, lane = t & 63, wave = t >> 6;
    const int wm = wave >> 1, wn = wave & 1;
    const int row0 = blockIdx.x * 64, col0 = blockIdx.y * 128;

    f32x4 acc[2][4];
#pragma unroll
    for (int m = 0; m < 2; ++m)
#pragma unroll
        for (int n = 0; n < 4; ++n) acc[m][n] = fzero4();

    const int srow = wave*16 + (lane >> 2);
    const int skk  = (lane & 3) * 8;
    const int ldsb = wave * 1024;

    auto STAGE = [&](int buf, int k0) {
        __builtin_amdgcn_global_load_lds(
            (const __attribute__((address_space(1))) void*)(A + (size_t)(row0 + srow)*Dn + k0 + skk),
            (__attribute__((address_space(3))) void*)((char*)As[buf] + ldsb), 16, 0, 0);
#pragma unroll
        for (int i = 0; i < 2; ++i)
            __builtin_amdgcn_global_load_lds(
                (const __attribute__((address_space(1))) void*)(Bw + (size_t)(col0 + i*64 + srow)*Dn + k0 + skk),
                (__attribute__((address_space(3))) void*)((char*)Bs[buf] + i*4096 + ldsb), 16, 0, 0);
    };

    STAGE(0, 0);
    __syncthreads();
    int cur = 0;
    for (int k0 = 0; k0 < Dn; k0 += 32) {
        if (k0 + 32 < Dn) STAGE(cur ^ 1, k0 + 32);
        short8 af[2], bf_[4];
#pragma unroll
        for (int m = 0; m < 2; ++m)
            af[m] = *(const short8*)((char*)As[cur] + (wm*32 + m*16 + (lane & 15))*64 + (lane >> 4)*16);
#pragma unroll
        for (int n = 0; n < 4; ++n)
            bf_[n] = *(const short8*)((char*)Bs[cur] + (wn*64 + n*16 + (lane & 15))*64 + (lane >> 4)*16);
        __builtin_amdgcn_s_setprio(1);
#pragma unroll
        for (int m = 0; m < 2; ++m)
#pragma unroll
            for (int n = 0; n < 4; ++n)
                acc[m][n] = __builtin_amdgcn_mfma_f32_16x16x32_bf16(af[m], bf_[n], acc[m][n], 0, 0, 0);
        __builtin_amdgcn_s_setprio(0);
        __syncthreads();
        cur ^= 1;
    }

#pragma unroll
    for (int n = 0; n < 4; ++n) {
        const int col = col0 + wn*64 + n*16 + (lane & 15);
        const float bv = bias[col];
#pragma unroll
        for (int m = 0; m < 2; ++m) {
            const int rb_ = row0 + wm*32 + m*16 + (lane>>4)*4;
#pragma unroll
            for (int i = 0; i < 4; ++i)
                C[(size_t)(rb_+i)*Dn + col] = acc[m][n][i] + bv;
        }
    }
}

// ---------------- flash attention fwd ----------------
// grid 512 (XCD-swizzled); 4 waves x 32 q-rows (QBLK=128); KV step 64.
// Double-buffered LDS V -> ONE barrier per step. l-sum via accumulated
// ones-row MFMA (off critical path). K/V reg prefetch one step deep.
#define VPL 1288

__device__ __forceinline__ void attn_step(
    const short8 (&ck)[4][2], const short8 (&cv)[2],
    short8 (&nk)[4][2], short8 (&nv)[2], int kvn, int buf,
    const short8 (&bq)[2][2], f32x4 (&o_)[2][4], float (&m_)[2], f32x4 (&lacc)[2],
    const __hip_bfloat16* K, const __hip_bfloat16* V, size_t base,
    int c, int g, int vrow, int vc, int vh, int vdst0, uint32_t atr, short* Vlds,
    const short8& ones)
{
    const float cexp = 0.18033688011112042f;   // log2(e)/sqrt(64)

    // 1. prefetch next step's K and V into regs (issue only)
    {
        const __hip_bfloat16* kp = K + base + (size_t)(kvn + c) * Dn + g*8;
#pragma unroll
        for (int sub = 0; sub < 4; ++sub)
#pragma unroll
            for (int ks = 0; ks < 2; ++ks)
                nk[sub][ks] = *(const short8*)(kp + (size_t)sub*16*Dn + ks*32);
        const __hip_bfloat16* vp = V + base + (size_t)(kvn + vrow) * Dn + vc*16 + vh*8;
        nv[0] = *(const short8*)vp;
        nv[1] = *(const short8*)(vp + (size_t)32*Dn);
    }

    // 2. S^T = K * Q
    f32x4 s_[2][4];
#pragma unroll
    for (int qs = 0; qs < 2; ++qs)
#pragma unroll
        for (int sub = 0; sub < 4; ++sub) s_[qs][sub] = fzero4();
    __builtin_amdgcn_s_setprio(1);
#pragma unroll
    for (int qs = 0; qs < 2; ++qs)
#pragma unroll
        for (int sub = 0; sub < 4; ++sub)
#pragma unroll
            for (int ks = 0; ks < 2; ++ks)
                s_[qs][sub] = __builtin_amdgcn_mfma_f32_16x16x32_bf16(
                    ck[sub][ks], bq[qs][ks], s_[qs][sub], 0, 0, 0);
    __builtin_amdgcn_s_setprio(0);

    // 3. online softmax (defer-max); P packed as PV B-fragments
    short8 pa[2][2];
#pragma unroll
    for (int qs = 0; qs < 2; ++qs) {
        float m01 = fmaxf(fmaxf(s_[qs][0][0], s_[qs][0][1]), fmaxf(s_[qs][0][2], s_[qs][0][3]));
        float m11 = fmaxf(fmaxf(s_[qs][1][0], s_[qs][1][1]), fmaxf(s_[qs][1][2], s_[qs][1][3]));
        float m21 = fmaxf(fmaxf(s_[qs][2][0], s_[qs][2][1]), fmaxf(s_[qs][2][2], s_[qs][2][3]));
        float m31 = fmaxf(fmaxf(s_[qs][3][0], s_[qs][3][1]), fmaxf(s_[qs][3][2], s_[qs][3][3]));
        float rm = fmaxf(fmaxf(m01, m11), fmaxf(m21, m31));
        rm = fmaxf(rm, __shfl_xor(rm, 16));
        rm = fmaxf(rm, __shfl_xor(rm, 32));
        if (!__all((rm - m_[qs]) * cexp <= 8.0f)) {
            const float mn = fmaxf(m_[qs], rm);
            const float sc = exp2f((m_[qs] - mn) * cexp);
            m_[qs] = mn;
#pragma unroll
            for (int i = 0; i < 4; ++i) lacc[qs][i] *= sc;
#pragma unroll
            for (int d = 0; d < 4; ++d)
#pragma unroll
                for (int i = 0; i < 4; ++i) o_[qs][d][i] *= sc;
        }
        const float mn = m_[qs];
#pragma unroll
        for (int kc = 0; kc < 2; ++kc)
#pragma unroll
            for (int hf = 0; hf < 2; ++hf)
#pragma unroll
                for (int i = 0; i < 4; ++i) {
                    const float p = exp2f((s_[qs][kc*2+hf][i] - mn) * cexp);
                    union { __hip_bfloat16 hb; short u; } cvp;
                    cvp.hb = __float2bfloat16(p);
                    pa[qs][kc][hf*4 + i] = cvp.u;
                }
        // l-sum on the matrix pipe, accumulated (read only at epilogue)
        lacc[qs] = __builtin_amdgcn_mfma_f32_16x16x32_bf16(ones, pa[qs][0], lacc[qs], 0, 0, 0);
        lacc[qs] = __builtin_amdgcn_mfma_f32_16x16x32_bf16(ones, pa[qs][1], lacc[qs], 0, 0, 0);
    }

    // 4. stage current V into LDS buf (single barrier per step)
    short* vb = Vlds + buf*4*VPL;
    *(short8*)(&vb[vdst0])       = cv[0];
    *(short8*)(&vb[vdst0 + 640]) = cv[1];
    asm volatile("s_waitcnt lgkmcnt(0)" ::: "memory");
    __builtin_amdgcn_s_barrier();
    __builtin_amdgcn_sched_barrier(0);

    // 5. PV: O^T += V^T * P^T (hardware transpose reads)
    const uint32_t atrb = atr + (uint32_t)buf*10304u;
    short4v tv[4][2][2];
#pragma unroll
    for (int d = 0; d < 4; ++d)
#pragma unroll
        for (int kc = 0; kc < 2; ++kc) {
            const uint32_t a = atrb + (uint32_t)(d*2576 + kc*1280);
            TR16(tv[d][kc][0], a);
            TR16(tv[d][kc][1], a + 640);
        }
    asm volatile("s_waitcnt lgkmcnt(0)" ::: "memory");
    __builtin_amdgcn_sched_barrier(0);
    __builtin_amdgcn_s_setprio(1);
#pragma unroll
    for (int d = 0; d < 4; ++d) {
        const short8 av0 = __builtin_shufflevector(tv[d][0][0], tv[d][0][1], 0,1,2,3,4,5,6,7);
        const short8 av1 = __builtin_shufflevector(tv[d][1][0], tv[d][1][1], 0,1,2,3,4,5,6,7);
#pragma unroll
        for (int qs = 0; qs < 2; ++qs) {
            o_[qs][d] = __builtin_amdgcn_mfma_f32_16x16x32_bf16(av0, pa[qs][0], o_[qs][d], 0, 0, 0);
            o_[qs][d] = __builtin_amdgcn_mfma_f32_16x16x32_bf16(av1, pa[qs][1], o_[qs][d], 0, 0, 0);
        }
    }
    __builtin_amdgcn_s_setprio(0);
}

__global__ __launch_bounds__(256, 2)
void attn_kernel(const __hip_bfloat16* __restrict__ Q,
                 const __hip_bfloat16* __restrict__ K,
                 const __hip_bfloat16* __restrict__ V,
                 __hip_bfloat16* __restrict__ O)
{
    __shared__ alignas(16) short Vlds[2*4*VPL];
    const int t = threadIdx.x, lane = t & 63, wave = t >> 6;
    const int g = lane >> 4, c = lane & 15;
    // XCD-aware bijective swizzle: 512 blocks -> 64 contiguous per XCD (4 heads/XCD)
    const int blk = (blockIdx.x & 7) * 64 + (blockIdx.x >> 3);
    const int qb = blk & 15;
    const int h  = (blk >> 4) & (Hn - 1);
    const int b  = blk >> 8;
    const size_t base = (size_t)b * Tn * Dn + (size_t)h * DHn;
    const int q0 = qb * 128 + wave * 32;

    short8 bq[2][2];
#pragma unroll
    for (int qs = 0; qs < 2; ++qs) {
        const __hip_bfloat16* qp = Q + base + (size_t)(q0 + qs*16 + c) * Dn + g*8;
        bq[qs][0] = *(const short8*)qp;
        bq[qs][1] = *(const short8*)(qp + 32);
    }
    short8 ones;
#pragma unroll
    for (int i = 0; i < 8; ++i) ones[i] = (short)0x3F80;

    f32x4 o_[2][4];
#pragma unroll
    for (int qs = 0; qs < 2; ++qs)
#pragma unroll
        for (int d = 0; d < 4; ++d) o_[qs][d] = fzero4();
    float m_[2] = {-3e38f, -3e38f};
    f32x4 lacc[2] = {fzero4(), fzero4()};

    const int vrow = t >> 3;
    const int vc   = (t >> 1) & 3;
    const int vh   = t & 1;
    const int vdst0 = vc*VPL + (vrow>>2)*80 + (vrow&3)*16 + vh*8;
    const uint32_t vbase = (uint32_t)(uintptr_t)(void*)Vlds;
    const uint32_t atr = vbase + (uint32_t)(g*160 + c*8);

    short8 akA[4][2], akB[4][2], vrA[2], vrB[2];
    {
        const __hip_bfloat16* kp = K + base + (size_t)c * Dn + g*8;
#pragma unroll
        for (int sub = 0; sub < 4; ++sub)
#pragma unroll
            for (int ks = 0; ks < 2; ++ks)
                akA[sub][ks] = *(const short8*)(kp + (size_t)sub*16*Dn + ks*32);
        const __hip_bfloat16* vp = V + base + (size_t)vrow * Dn + vc*16 + vh*8;
        vrA[0] = *(const short8*)vp;
        vrA[1] = *(const short8*)(vp + (size_t)32*Dn);
    }

    for (int kv0 = 0; kv0 < Tn; kv0 += 128) {
        attn_step(akA, vrA, akB, vrB, kv0 + 64, 0, bq, o_, m_, lacc,
                  K, V, base, c, g, vrow, vc, vh, vdst0, atr, Vlds, ones);
        const int kvn = (kv0 + 128 < Tn) ? kv0 + 128 : 0;
        attn_step(akB, vrB, akA, vrA, kvn, 1, bq, o_, m_, lacc,
                  K, V, base, c, g, vrow, vc, vh, vdst0, atr, Vlds, ones);
    }

#pragma unroll
    for (int qs = 0; qs < 2; ++qs) {
        const float inv = 1.f / lacc[qs][0];
        __hip_bfloat16* op = O + base + (size_t)(q0 + qs*16 + c) * Dn + g*4;
#pragma unroll
        for (int d = 0; d < 4; ++d) {
            union { __hip_bfloat16 hb[4]; ushort4 u4; } w;
#pragma unroll
            for (int i = 0; i < 4; ++i) w.hb[i] = __float2bfloat16(o_[qs][d][i] * inv);
            *(ushort4*)(op + d*16) = w.u4;
        }
    }
}

extern "C" void kernel_launch(void* const* d_in, const int* in_sizes, int n_in,
                              void* d_out, int out_size, void* d_ws, size_t ws_size,
                              hipStream_t stream)
{
    (void)in_sizes; (void)n_in; (void)out_size; (void)ws_size;
    const float* q    = (const float*)d_in[0];
    const float* k    = (const float*)d_in[1];
    const float* v    = (const float*)d_in[2];
    const float* wq_w = (const float*)d_in[3];
    const float* wq_b = (const float*)d_in[4];
    const float* wk_w = (const float*)d_in[5];
    const float* wk_b = (const float*)d_in[6];
    const float* wv_w = (const float*)d_in[7];
    const float* wv_b = (const float*)d_in[8];
    const float* wo_w = (const float*)d_in[9];
    const float* wo_b = (const float*)d_in[10];

    char* ws = (char*)d_ws;
    const size_t S1 = (size_t)Mn * Dn * 2;
    const size_t W  = (size_t)Dn * Dn * 2;
    __hip_bfloat16* qb  = (__hip_bfloat16*)(ws);
    __hip_bfloat16* kb  = (__hip_bfloat16*)(ws + S1);
    __hip_bfloat16* vb  = (__hip_bfloat16*)(ws + 2*S1);
    __hip_bfloat16* wqb = (__hip_bfloat16*)(ws + 3*S1);
    __hip_bfloat16* wkb = (__hip_bfloat16*)(ws + 3*S1 + W);
    __hip_bfloat16* wvb = (__hip_bfloat16*)(ws + 3*S1 + 2*W);
    __hip_bfloat16* wob = (__hip_bfloat16*)(ws + 3*S1 + 3*W);
    __hip_bfloat16* Qp  = (__hip_bfloat16*)(ws + 3*S1 + 4*W);
    __hip_bfloat16* Kp  = (__hip_bfloat16*)(ws + 4*S1 + 4*W);
    __hip_bfloat16* Vp  = (__hip_bfloat16*)(ws + 5*S1 + 4*W);
    __hip_bfloat16* Ap  = (__hip_bfloat16*)(ws + 6*S1 + 4*W);

    const int nQKV = Mn * Dn;
    const int nW   = Dn * Dn;
    cvt3_kernel<<<dim3(nQKV/2048, 3), 256, 0, stream>>>(q, k, v, qb, kb, vb, nQKV);
    cvt4_kernel<<<dim3(nW/2048, 4), 256, 0, stream>>>(wq_w, wk_w, wv_w, wo_w,
                                                      wqb, wkb, wvb, wob, nW);

    gemm_qkv_kernel<<<dim3(Mn/128, 24), 256, 0, stream>>>(
        qb, kb, vb, wqb, wkb, wvb, wq_b, wk_b, wv_b, Qp, Kp, Vp);

    attn_kernel<<<Bn*Hn*(Tn/128), 256, 0, stream>>>(Qp, Kp, Vp, Ap);

    gemm_out_kernel<<<dim3(Mn/64, Dn/128), 256, 0, stream>>>(Ap, wob, wo_b, (float*)d_out);
}